// Round 6
// baseline (223.720 us; speedup 1.0000x reference)
//
#include <hip/hip_runtime.h>
#include <stdint.h>

#define BSZ 2
#define TT 2048
#define DD 1024
#define HH 16
#define HD 64

typedef __bf16 bf16x8 __attribute__((ext_vector_type(8)));
typedef float f32x4 __attribute__((ext_vector_type(4)));

// fast exp2: single v_exp_f32 (builtin if available, else inline asm + hazard nop)
#if __has_builtin(__builtin_amdgcn_exp2f)
__device__ __forceinline__ float fexp2(float x) { return __builtin_amdgcn_exp2f(x); }
#else
__device__ __forceinline__ float fexp2(float x) {
    float r; asm("v_exp_f32 %0, %1\n\ts_nop 1" : "=v"(r) : "v"(x)); return r;
}
#endif

__device__ __forceinline__ unsigned short f2bf(float f) {
    union { float f; unsigned u; } c; c.f = f;
    unsigned u = c.u;
    unsigned r = u + 0x7fffu + ((u >> 16) & 1u);
    return (unsigned short)(r >> 16);
}
__device__ __forceinline__ unsigned fasu(float f) {
    union { float f; unsigned u; } c; c.f = f; return c.u;
}

union U4BF { uint4 u; bf16x8 b; };
__device__ __forceinline__ bf16x8 as_bf8(uint4 v) { U4BF c; c.u = v; return c.b; }

// ---- async global->LDS, 16B per lane; LDS dst = wave-uniform base + lane*16 ----
#if __has_builtin(__builtin_amdgcn_global_load_lds)
__device__ __forceinline__ void gl_lds16(const ushort* g, ushort* l) {
    __builtin_amdgcn_global_load_lds(
        (const __attribute__((address_space(1))) uint32_t*)g,
        (__attribute__((address_space(3))) uint32_t*)l, 16, 0, 0);
}
#define GLL_LANE 1
#else
__device__ __forceinline__ void gl_lds16_fallback(const ushort* g, ushort* l, int lane) {
    *(uint4*)(l + lane * 8) = *(const uint4*)(g);
}
#define GLL_LANE 0
#endif

// ---------------- prep: y<3 -> fp32->bf16 cvt of q/k/v ; y==3 -> W transpose ----
__global__ __launch_bounds__(256)
void prep(const float* __restrict__ q, const float* __restrict__ k,
          const float* __restrict__ v,
          const float* __restrict__ W0, const float* __restrict__ W1,
          const float* __restrict__ W2, const float* __restrict__ W3,
          ushort* __restrict__ xq, ushort* __restrict__ xk, ushort* __restrict__ xv,
          ushort* __restrict__ T0, ushort* __restrict__ T1,
          ushort* __restrict__ T2, ushort* __restrict__ T3) {
    __shared__ float sh[32][33];
    const int y = blockIdx.y;
    if (y < 3) {
        const float* in = (y == 0) ? q : (y == 1) ? k : v;
        ushort* out = (y == 0) ? xq : (y == 1) ? xk : xv;
        int i = blockIdx.x * 256 + threadIdx.x;
        float4 val = ((const float4*)in)[i];
        ushort4 o;
        o.x = f2bf(val.x); o.y = f2bf(val.y); o.z = f2bf(val.z); o.w = f2bf(val.w);
        ((ushort4*)out)[i] = o;
    } else {
        const int x = blockIdx.x;
        const float* src; ushort* dst;
        switch (x >> 10) {
            case 0:  src = W0; dst = T0; break;
            case 1:  src = W1; dst = T1; break;
            case 2:  src = W2; dst = T2; break;
            default: src = W3; dst = T3; break;
        }
        const int tile = x & 1023;
        const int k0 = (tile >> 5) * 32, n0 = (tile & 31) * 32;
        const int tx = threadIdx.x & 31, ty = threadIdx.x >> 5;  // ty 0..7
        #pragma unroll
        for (int p = 0; p < 4; ++p)
            sh[ty + 8 * p][tx] = src[(size_t)(k0 + ty + 8 * p) * DD + n0 + tx];
        __syncthreads();
        #pragma unroll
        for (int p = 0; p < 4; ++p)
            dst[(size_t)(n0 + ty + 8 * p) * DD + k0 + tx] = f2bf(sh[tx][ty + 8 * p]);
    }
}

// ---------------- BMx128 bf16 MFMA GEMM with global_load_lds staging ----------------
// OUT_MODE 0: z-batched QKV. z<2 -> bf16 [bh][t][d]; z==2 -> bf16 Vt [bh][d][t].
// OUT_MODE 1: fp32 out row-major [4096][1024].
template<int BM, int OUT_MODE>
__global__ __launch_bounds__(256)
void gemm_mfma(const ushort* __restrict__ A0, const ushort* __restrict__ B0,
               const float* __restrict__ c0, void* __restrict__ d0,
               const ushort* __restrict__ A1, const ushort* __restrict__ B1,
               const float* __restrict__ c1, void* __restrict__ d1,
               const ushort* __restrict__ A2, const ushort* __restrict__ B2,
               const float* __restrict__ c2, void* __restrict__ d2) {
    constexpr int TI = 4;
    constexpr int TJ = (BM == 128) ? 4 : 2;
    constexpr int WC = (BM == 128) ? 2 : 4;
    __shared__ __attribute__((aligned(16))) ushort As[BM][32];
    __shared__ __attribute__((aligned(16))) ushort Bs[128][32];
    const ushort* A; const ushort* Bt; const float* bias; void* outp;
    const int z = blockIdx.z;
    switch (z) {
        case 0:  A = A0; Bt = B0; bias = c0; outp = d0; break;
        case 1:  A = A1; Bt = B1; bias = c1; outp = d1; break;
        default: A = A2; Bt = B2; bias = c2; outp = d2; break;
    }
    const int tid  = threadIdx.x;
    const int lane = tid & 63, w = tid >> 6;
    const int wr = w / WC, wc = w % WC;
    const int ln = lane & 15, quad = lane >> 4;
    const int m0 = blockIdx.y * BM, n0 = blockIdx.x * 128;

    const f32x4 zero = {0.f, 0.f, 0.f, 0.f};
    f32x4 acc[TI][TJ];
    #pragma unroll
    for (int i = 0; i < TI; ++i)
        #pragma unroll
        for (int j = 0; j < TJ; ++j) acc[i][j] = zero;

    const int lr  = lane >> 2;        // row within 16-row stripe
    const int lc8 = (lane & 3) * 8;   // 0,8,16,24

    for (int kb = 0; kb < 1024; kb += 32) {
        #pragma unroll
        for (int it = 0; it < BM / 64; ++it) {
            int r0 = it * 64 + w * 16;
#if GLL_LANE
            gl_lds16(A + (size_t)(m0 + r0 + lr) * 1024 + kb + lc8, &As[r0][0]);
#else
            gl_lds16_fallback(A + (size_t)(m0 + r0 + lr) * 1024 + kb + lc8, &As[r0][0], lane);
#endif
        }
        #pragma unroll
        for (int it = 0; it < 2; ++it) {
            int r0 = it * 64 + w * 16;
#if GLL_LANE
            gl_lds16(Bt + (size_t)(n0 + r0 + lr) * 1024 + kb + lc8, &Bs[r0][0]);
#else
            gl_lds16_fallback(Bt + (size_t)(n0 + r0 + lr) * 1024 + kb + lc8, &Bs[r0][0], lane);
#endif
        }
        __syncthreads();
        bf16x8 af[TI], bfr[TJ];
        #pragma unroll
        for (int i = 0; i < TI; ++i)
            af[i] = as_bf8(*(const uint4*)&As[wr * 64 + i * 16 + ln][quad * 8]);
        #pragma unroll
        for (int j = 0; j < TJ; ++j)
            bfr[j] = as_bf8(*(const uint4*)&Bs[wc * (TJ * 16) + j * 16 + ln][quad * 8]);
        #pragma unroll
        for (int i = 0; i < TI; ++i)
            #pragma unroll
            for (int j = 0; j < TJ; ++j)
                acc[i][j] = __builtin_amdgcn_mfma_f32_16x16x32_bf16(af[i], bfr[j], acc[i][j], 0, 0, 0);
        __syncthreads();
    }

    #pragma unroll
    for (int j = 0; j < TJ; ++j) {
        int n = n0 + wc * (TJ * 16) + j * 16 + ln;
        float bv = bias[n];
        #pragma unroll
        for (int i = 0; i < TI; ++i) {
            int mb = m0 + wr * 64 + i * 16 + quad * 4;
            if (OUT_MODE == 0 && z == 2) {
                // V: write transposed Vt[bh][d][t], t = mb..mb+3 contiguous
                int b = mb >> 11, t = mb & 2047, h = n >> 6, d = n & 63;
                ushort4 pk;
                pk.x = f2bf(acc[i][j][0] + bv);
                pk.y = f2bf(acc[i][j][1] + bv);
                pk.z = f2bf(acc[i][j][2] + bv);
                pk.w = f2bf(acc[i][j][3] + bv);
                *(ushort4*)((ushort*)outp + ((size_t)((b * HH + h) * HD + d)) * TT + t) = pk;
            } else {
                #pragma unroll
                for (int r = 0; r < 4; ++r) {
                    int m = mb + r;
                    float v = acc[i][j][r] + bv;
                    if (OUT_MODE == 0) {
                        int b = m >> 11, t = m & 2047, h = n >> 6, d = n & 63;
                        ((ushort*)outp)[(((size_t)(b * HH + h)) * TT + t) * HD + d] = f2bf(v);
                    } else {
                        ((float*)outp)[(size_t)m * 1024 + n] = v;
                    }
                }
            }
        }
    }
}

// ---------------- flash attention v5: v4 + conflict-free Ps swizzle + setprio ------
// 1024 blocks, 1:1 static items. Item = (b, h, 64 q-rows). 4 waves x 16 q-rows each
// consume the SAME K/V tile double-buffered in LDS. 40KB LDS -> 4 blocks/CU.
// Ps physical unit = logical unit ^ (q&7): every 8-lane group of the b128 read
// covers all 8 16B-units -> conflict-free (the round-4 [64]-stride layout with
// ^(ln>>2) was an 8-way conflict: bank depended only on the 4-valued unit index).
// Qh,Kh: [bh][t][d]   Vtg: [bh][d][t]   out: [B][T][D] bf16
__global__ __launch_bounds__(256)
void attn_kernel(const ushort* __restrict__ Qh, const ushort* __restrict__ Kh,
                 const ushort* __restrict__ Vtg, ushort* __restrict__ outp) {
    __shared__ __attribute__((aligned(16))) ushort Ks[2][64][64];  // [buf][krow][d]
    __shared__ __attribute__((aligned(16))) ushort Vs[2][64][64];  // [buf][d][t]
    __shared__ __attribute__((aligned(16))) ushort Ps[4][16][64];  // per-wave P xpose

    const int tid  = threadIdx.x;
    const int lane = tid & 63, w = tid >> 6;
    const int ln = lane & 15, quad = lane >> 4;
    const int rr = lane >> 3, jj = lane & 7;   // staging: row-in-8 / 16B-unit
    const int sswz = (jj ^ rr) * 8;            // pre-swizzled source unit (ushorts)
    const int l7 = ln & 7;
    const int u0 = (quad ^ l7) * 8;            // K/V hf=0 read unit offset (ushorts)
    const int u1 = u0 ^ 32;                    // hf=1 ( ^4 on the unit index )

    bf16x8 ones;
    {
        union { ushort us[8]; bf16x8 v; } uu;
        #pragma unroll
        for (int p = 0; p < 8; ++p) uu.us[p] = 0x3F80;
        ones = uu.v;
    }
    const f32x4 zero = {0.f, 0.f, 0.f, 0.f};
    const float c1 = 0.125f * 1.44269504f;  // scale*log2e

    // first 512 bids: heavy-first items; second 512: reversed -> heavy+light mix/CU
    const int bid = blockIdx.x;
    const int item = (bid < 512) ? bid : (1535 - bid);   // bijection on [0,1024)
    const int h = 15 - (item >> 6);
    const int sub = item & 63;
    const int b = sub & 1;
    const int qt = sub >> 1;                 // 0..31, 64 q-rows each
    const int bh = b * 16 + h;
    const int qb0 = qt * 64;
    const int qbw = qb0 + w * 16;            // this wave's 16 q-rows
    const float slope2 = exp2f(-0.5f * (float)(h + 1)) * 1.44269504f;
    const size_t base = (size_t)bh * (TT * HD);

    // ALiBi band (union over the 64 rows); per-wave sub-band for compute skip
    const int D = (int)ceilf(18.0f / slope2);
    int lo = qb0 - D;
    int kt_lo = (lo > 0) ? (lo >> 6) : 0;
    int kt_hi = (qb0 + 64 + D + 63) >> 6;
    if (kt_hi > TT / 64) kt_hi = TT / 64;
    int wl = qbw - D;
    int my_lo = (wl > 0) ? (wl >> 6) : 0;
    if (my_lo < kt_lo) my_lo = kt_lo;
    int my_hi = (qbw + 16 + D + 63) >> 6;
    if (my_hi > kt_hi) my_hi = kt_hi;

    // Q fragments (A-layout) for this wave's 16 rows
    bf16x8 qa[2];
    {
        const uint4* qp = (const uint4*)(Qh + base + (size_t)(qbw + ln) * HD);
        qa[0] = as_bf8(qp[quad]);
        qa[1] = as_bf8(qp[4 + quad]);
    }
    f32x4 o[4], lsum = zero;
    #pragma unroll
    for (int dn = 0; dn < 4; ++dn) o[dn] = zero;
    float qrf[4];
    #pragma unroll
    for (int r = 0; r < 4; ++r)
        qrf[r] = (float)(qbw + quad * 4 + r);

    // stage one K tile (64x64, rows contiguous 128B) + one V tile (64 d-rows x 64 t,
    // rows strided 4KB) into LDS buf; each wave stages 2KB of each (2 instrs).
    // LDS[r][j] = G[r][j ^ (r&7)]  (source pre-swizzle; dest linear)
    auto STAGE = [&](int bufi, int kt) {
        #pragma unroll
        for (int ii = 0; ii < 2; ++ii) {
            const int r0 = (w * 2 + ii) * 8;   // r0 multiple of 8 -> (r0+rr)&7 == rr
#if GLL_LANE
            gl_lds16(Kh + base + (size_t)(kt * 64 + r0 + rr) * HD + sswz, &Ks[bufi][r0][0]);
            gl_lds16(Vtg + base + (size_t)(r0 + rr) * TT + kt * 64 + sswz, &Vs[bufi][r0][0]);
#else
            gl_lds16_fallback(Kh + base + (size_t)(kt * 64 + r0 + rr) * HD + sswz, &Ks[bufi][r0][0], lane);
            gl_lds16_fallback(Vtg + base + (size_t)(r0 + rr) * TT + kt * 64 + sswz, &Vs[bufi][r0][0], lane);
#endif
        }
    };

    STAGE(0, kt_lo);
    int buf = 0;
    for (int kt = kt_lo; kt < kt_hi; ++kt) {
        asm volatile("s_waitcnt vmcnt(0)" ::: "memory");  // my staging for buf done
        __syncthreads();  // everyone's staging done; everyone done reading buf^1
        if (kt + 1 < kt_hi) STAGE(buf ^ 1, kt + 1);

        if (kt >= my_lo && kt < my_hi) {
            // S = Q K^T  (K frags from swizzled LDS)
            f32x4 s[4];
            __builtin_amdgcn_s_setprio(1);
            #pragma unroll
            for (int n = 0; n < 4; ++n) {
                bf16x8 b0 = as_bf8(*(const uint4*)&Ks[buf][n * 16 + ln][u0]);
                bf16x8 b1 = as_bf8(*(const uint4*)&Ks[buf][n * 16 + ln][u1]);
                f32x4 zz = zero;
                zz = __builtin_amdgcn_mfma_f32_16x16x32_bf16(qa[0], b0, zz, 0, 0, 0);
                s[n] = __builtin_amdgcn_mfma_f32_16x16x32_bf16(qa[1], b1, zz, 0, 0, 0);
            }
            __builtin_amdgcn_s_setprio(0);

            // p = exp2(S*c1 - slope2*|q-k|), truncate bf16, swizzled LDS store.
            // phys unit = logical unit ^ (q&7); q = quad*4+r -> q&7 = (quad&1)*4+r
            #pragma unroll
            for (int n = 0; n < 4; ++n) {
                float kg = (float)(kt * 64 + n * 16 + ln);
                const int lun = 2 * n + (ln >> 3);   // logical unit of this lane's k
                #pragma unroll
                for (int r = 0; r < 4; ++r) {
                    float d = qrf[r] - kg;
                    float arg = fmaf(s[n][r], c1, -slope2 * fabsf(d));
                    float p = fexp2(arg);
                    const int bswz = ((lun ^ ((quad & 1) * 4 + r)) * 8) + (ln & 7);
                    Ps[w][quad * 4 + r][bswz] = (ushort)(fasu(p) >> 16);
                }
            }
            // no barrier: Ps[w] is wave-private

            // O += P V ; lsum += P * ones  (V frags from swizzled LDS)
            __builtin_amdgcn_s_setprio(1);
            #pragma unroll
            for (int hf = 0; hf < 2; ++hf) {
                bf16x8 ap = as_bf8(*(const uint4*)&Ps[w][ln][((hf * 4 + quad) ^ (ln & 7)) * 8]);
                const int uu = hf ? u1 : u0;
                #pragma unroll
                for (int dn = 0; dn < 4; ++dn) {
                    bf16x8 bv = as_bf8(*(const uint4*)&Vs[buf][dn * 16 + ln][uu]);
                    o[dn] = __builtin_amdgcn_mfma_f32_16x16x32_bf16(ap, bv, o[dn], 0, 0, 0);
                }
                lsum = __builtin_amdgcn_mfma_f32_16x16x32_bf16(ap, ones, lsum, 0, 0, 0);
            }
            __builtin_amdgcn_s_setprio(0);
        }
        buf ^= 1;
    }

    // -------- epilogue: no merge; each wave owns its 16 rows --------
    #pragma unroll
    for (int r = 0; r < 4; ++r) {
        float inv = __builtin_amdgcn_rcpf(lsum[r]);
        int q = qbw + quad * 4 + r;
        size_t ob = ((size_t)(b * TT + q)) * DD + h * HD;
        #pragma unroll
        for (int dn = 0; dn < 4; ++dn)
            outp[ob + dn * 16 + ln] = f2bf(o[dn][r] * inv);
    }
}

extern "C" void kernel_launch(void* const* d_in, const int* in_sizes, int n_in,
                              void* d_out, int out_size, void* d_ws, size_t ws_size,
                              hipStream_t stream) {
    const float* query = (const float*)d_in[0];
    const float* key   = (const float*)d_in[1];
    const float* value = (const float*)d_in[2];
    const float* Wq = (const float*)d_in[3];
    const float* bq = (const float*)d_in[4];
    const float* Wk = (const float*)d_in[5];
    const float* bk = (const float*)d_in[6];
    const float* Wv = (const float*)d_in[7];
    const float* bv = (const float*)d_in[8];
    const float* Wo = (const float*)d_in[9];
    const float* bo = (const float*)d_in[10];
    float* out = (float*)d_out;

    char* ws = (char*)d_ws;
    const size_t MB = 1024 * 1024;
    ushort* Xq  = (ushort*)(ws + 0);
    ushort* Xk  = (ushort*)(ws + 8 * MB);
    ushort* Xv  = (ushort*)(ws + 16 * MB);
    ushort* Wtq = (ushort*)(ws + 24 * MB);
    ushort* Wtk = (ushort*)(ws + 26 * MB);
    ushort* Wtv = (ushort*)(ws + 28 * MB);
    ushort* Wto = (ushort*)(ws + 30 * MB);
    ushort* Qh  = (ushort*)(ws + 32 * MB);
    ushort* Kh  = (ushort*)(ws + 40 * MB);
    ushort* Vt  = (ushort*)(ws + 48 * MB);  // written transposed by gemm z==2
    ushort* attn = (ushort*)(ws + 0);       // reuse Xq (free after QKV gemm)

    // conversions + weight transpose, one launch
    prep<<<dim3(4096, 4), 256, 0, stream>>>(query, key, value, Wq, Wk, Wv, Wo,
                                            Xq, Xk, Xv, Wtq, Wtk, Wtv, Wto);

    // QKV projections: one z-batched launch; z==2 writes V transposed
    gemm_mfma<128, 0><<<dim3(8, 32, 3), 256, 0, stream>>>(
        Xq, Wtq, bq, Qh,  Xk, Wtk, bk, Kh,  Xv, Wtv, bv, Vt);

    // flash attention: 1024 blocks, 1:1 static (b,h,64-q-row) items, 4 blocks/CU
    attn_kernel<<<dim3(1024), 256, 0, stream>>>(Qh, Kh, Vt, attn);

    // output projection: 128x128 tiles, 256 blocks (BM=64 was ~200-340 TF; the
    // 128^2 tile doubles per-wave MFMA density -> ladder says ~2x)
    gemm_mfma<128, 1><<<dim3(8, 32, 1), 256, 0, stream>>>(
        attn, Wto, bo, out,  attn, Wto, bo, out,  attn, Wto, bo, out);
}

// Round 7
// 217.405 us; speedup vs baseline: 1.0290x; 1.0290x over previous
//
#include <hip/hip_runtime.h>
#include <stdint.h>

#define BSZ 2
#define TT 2048
#define DD 1024
#define HH 16
#define HD 64

typedef __bf16 bf16x8 __attribute__((ext_vector_type(8)));
typedef float f32x4 __attribute__((ext_vector_type(4)));

// fast exp2: single v_exp_f32 (builtin if available, else inline asm + hazard nop)
#if __has_builtin(__builtin_amdgcn_exp2f)
__device__ __forceinline__ float fexp2(float x) { return __builtin_amdgcn_exp2f(x); }
#else
__device__ __forceinline__ float fexp2(float x) {
    float r; asm("v_exp_f32 %0, %1\n\ts_nop 1" : "=v"(r) : "v"(x)); return r;
}
#endif

__device__ __forceinline__ unsigned short f2bf(float f) {
    union { float f; unsigned u; } c; c.f = f;
    unsigned u = c.u;
    unsigned r = u + 0x7fffu + ((u >> 16) & 1u);
    return (unsigned short)(r >> 16);
}
__device__ __forceinline__ unsigned fasu(float f) {
    union { float f; unsigned u; } c; c.f = f; return c.u;
}

union U4BF { uint4 u; bf16x8 b; };
__device__ __forceinline__ bf16x8 as_bf8(uint4 v) { U4BF c; c.u = v; return c.b; }

// ---- async global->LDS, 16B per lane; LDS dst = wave-uniform base + lane*16 ----
#if __has_builtin(__builtin_amdgcn_global_load_lds)
__device__ __forceinline__ void gl_lds16(const ushort* g, ushort* l) {
    __builtin_amdgcn_global_load_lds(
        (const __attribute__((address_space(1))) uint32_t*)g,
        (__attribute__((address_space(3))) uint32_t*)l, 16, 0, 0);
}
#define GLL_LANE 1
#else
__device__ __forceinline__ void gl_lds16_fallback(const ushort* g, ushort* l, int lane) {
    *(uint4*)(l + lane * 8) = *(const uint4*)(g);
}
#define GLL_LANE 0
#endif

// ---------------- prep: y<3 -> fp32->bf16 cvt of q/k/v ; y==3 -> W transpose ----
__global__ __launch_bounds__(256)
void prep(const float* __restrict__ q, const float* __restrict__ k,
          const float* __restrict__ v,
          const float* __restrict__ W0, const float* __restrict__ W1,
          const float* __restrict__ W2, const float* __restrict__ W3,
          ushort* __restrict__ xq, ushort* __restrict__ xk, ushort* __restrict__ xv,
          ushort* __restrict__ T0, ushort* __restrict__ T1,
          ushort* __restrict__ T2, ushort* __restrict__ T3) {
    __shared__ float sh[32][33];
    const int y = blockIdx.y;
    if (y < 3) {
        const float* in = (y == 0) ? q : (y == 1) ? k : v;
        ushort* out = (y == 0) ? xq : (y == 1) ? xk : xv;
        int i = blockIdx.x * 256 + threadIdx.x;
        float4 val = ((const float4*)in)[i];
        ushort4 o;
        o.x = f2bf(val.x); o.y = f2bf(val.y); o.z = f2bf(val.z); o.w = f2bf(val.w);
        ((ushort4*)out)[i] = o;
    } else {
        const int x = blockIdx.x;
        const float* src; ushort* dst;
        switch (x >> 10) {
            case 0:  src = W0; dst = T0; break;
            case 1:  src = W1; dst = T1; break;
            case 2:  src = W2; dst = T2; break;
            default: src = W3; dst = T3; break;
        }
        const int tile = x & 1023;
        const int k0 = (tile >> 5) * 32, n0 = (tile & 31) * 32;
        const int tx = threadIdx.x & 31, ty = threadIdx.x >> 5;  // ty 0..7
        #pragma unroll
        for (int p = 0; p < 4; ++p)
            sh[ty + 8 * p][tx] = src[(size_t)(k0 + ty + 8 * p) * DD + n0 + tx];
        __syncthreads();
        #pragma unroll
        for (int p = 0; p < 4; ++p)
            dst[(size_t)(n0 + ty + 8 * p) * DD + k0 + tx] = f2bf(sh[tx][ty + 8 * p]);
    }
}

// ---------------- BMx128 bf16 MFMA GEMM with global_load_lds staging ----------------
// OUT_MODE 0: z-batched QKV. z<2 -> bf16 [bh][t][d]; z==2 -> bf16 Vt [bh][d][t].
// OUT_MODE 1: fp32 out row-major [4096][1024].
template<int BM, int OUT_MODE>
__global__ __launch_bounds__(256)
void gemm_mfma(const ushort* __restrict__ A0, const ushort* __restrict__ B0,
               const float* __restrict__ c0, void* __restrict__ d0,
               const ushort* __restrict__ A1, const ushort* __restrict__ B1,
               const float* __restrict__ c1, void* __restrict__ d1,
               const ushort* __restrict__ A2, const ushort* __restrict__ B2,
               const float* __restrict__ c2, void* __restrict__ d2) {
    constexpr int TI = 4;
    constexpr int TJ = (BM == 128) ? 4 : 2;
    constexpr int WC = (BM == 128) ? 2 : 4;
    __shared__ __attribute__((aligned(16))) ushort As[BM][32];
    __shared__ __attribute__((aligned(16))) ushort Bs[128][32];
    const ushort* A; const ushort* Bt; const float* bias; void* outp;
    const int z = blockIdx.z;
    switch (z) {
        case 0:  A = A0; Bt = B0; bias = c0; outp = d0; break;
        case 1:  A = A1; Bt = B1; bias = c1; outp = d1; break;
        default: A = A2; Bt = B2; bias = c2; outp = d2; break;
    }
    const int tid  = threadIdx.x;
    const int lane = tid & 63, w = tid >> 6;
    const int wr = w / WC, wc = w % WC;
    const int ln = lane & 15, quad = lane >> 4;
    const int m0 = blockIdx.y * BM, n0 = blockIdx.x * 128;

    const f32x4 zero = {0.f, 0.f, 0.f, 0.f};
    f32x4 acc[TI][TJ];
    #pragma unroll
    for (int i = 0; i < TI; ++i)
        #pragma unroll
        for (int j = 0; j < TJ; ++j) acc[i][j] = zero;

    const int lr  = lane >> 2;        // row within 16-row stripe
    const int lc8 = (lane & 3) * 8;   // 0,8,16,24

    for (int kb = 0; kb < 1024; kb += 32) {
        #pragma unroll
        for (int it = 0; it < BM / 64; ++it) {
            int r0 = it * 64 + w * 16;
#if GLL_LANE
            gl_lds16(A + (size_t)(m0 + r0 + lr) * 1024 + kb + lc8, &As[r0][0]);
#else
            gl_lds16_fallback(A + (size_t)(m0 + r0 + lr) * 1024 + kb + lc8, &As[r0][0], lane);
#endif
        }
        #pragma unroll
        for (int it = 0; it < 2; ++it) {
            int r0 = it * 64 + w * 16;
#if GLL_LANE
            gl_lds16(Bt + (size_t)(n0 + r0 + lr) * 1024 + kb + lc8, &Bs[r0][0]);
#else
            gl_lds16_fallback(Bt + (size_t)(n0 + r0 + lr) * 1024 + kb + lc8, &Bs[r0][0], lane);
#endif
        }
        __syncthreads();
        bf16x8 af[TI], bfr[TJ];
        #pragma unroll
        for (int i = 0; i < TI; ++i)
            af[i] = as_bf8(*(const uint4*)&As[wr * 64 + i * 16 + ln][quad * 8]);
        #pragma unroll
        for (int j = 0; j < TJ; ++j)
            bfr[j] = as_bf8(*(const uint4*)&Bs[wc * (TJ * 16) + j * 16 + ln][quad * 8]);
        #pragma unroll
        for (int i = 0; i < TI; ++i)
            #pragma unroll
            for (int j = 0; j < TJ; ++j)
                acc[i][j] = __builtin_amdgcn_mfma_f32_16x16x32_bf16(af[i], bfr[j], acc[i][j], 0, 0, 0);
        __syncthreads();
    }

    #pragma unroll
    for (int j = 0; j < TJ; ++j) {
        int n = n0 + wc * (TJ * 16) + j * 16 + ln;
        float bv = bias[n];
        #pragma unroll
        for (int i = 0; i < TI; ++i) {
            int mb = m0 + wr * 64 + i * 16 + quad * 4;
            if (OUT_MODE == 0 && z == 2) {
                // V: write transposed Vt[bh][d][t], t = mb..mb+3 contiguous
                int b = mb >> 11, t = mb & 2047, h = n >> 6, d = n & 63;
                ushort4 pk;
                pk.x = f2bf(acc[i][j][0] + bv);
                pk.y = f2bf(acc[i][j][1] + bv);
                pk.z = f2bf(acc[i][j][2] + bv);
                pk.w = f2bf(acc[i][j][3] + bv);
                *(ushort4*)((ushort*)outp + ((size_t)((b * HH + h) * HD + d)) * TT + t) = pk;
            } else {
                #pragma unroll
                for (int r = 0; r < 4; ++r) {
                    int m = mb + r;
                    float v = acc[i][j][r] + bv;
                    if (OUT_MODE == 0) {
                        int b = m >> 11, t = m & 2047, h = n >> 6, d = n & 63;
                        ((ushort*)outp)[(((size_t)(b * HH + h)) * TT + t) * HD + d] = f2bf(v);
                    } else {
                        ((float*)outp)[(size_t)m * 1024 + n] = v;
                    }
                }
            }
        }
    }
}

// ---------------- flash attention v6: 8-wave 128-row blocks ------------------------
// 512 blocks x 512 threads, 1:1 static items. Item = (b, h, 128 q-rows). 8 waves x
// 16 q-rows each consume the SAME K/V tile double-buffered in LDS (staging per
// 16-row-wave halves vs v5's 64-row blocks). A heavy block running ALONE in the
// tail now has 2 waves/SIMD and is LDS/VALU-throughput-bound (~700cy/tile for 2x
// the q-coverage) instead of 1-wave latency-bound (v5's ~1300cy/tile tail).
// LDS 48KB (ring 32K + Ps 8x2K) -> 2 blocks/CU. Reversed 2nd half pairs heavy+light.
// Per-wave sub-band skip keeps total wave-visits ~= v5.
// Qh,Kh: [bh][t][d]   Vtg: [bh][d][t]   out: [B][T][D] bf16
__global__ __launch_bounds__(512)
void attn_kernel(const ushort* __restrict__ Qh, const ushort* __restrict__ Kh,
                 const ushort* __restrict__ Vtg, ushort* __restrict__ outp) {
    __shared__ __attribute__((aligned(16))) ushort Ks[2][64][64];  // [buf][krow][d]
    __shared__ __attribute__((aligned(16))) ushort Vs[2][64][64];  // [buf][d][t]
    __shared__ __attribute__((aligned(16))) ushort Ps[8][16][64];  // per-wave P xpose

    const int tid  = threadIdx.x;
    const int lane = tid & 63, w = tid >> 6;   // w = 0..7
    const int ln = lane & 15, quad = lane >> 4;
    const int rr = lane >> 3, jj = lane & 7;   // staging: row-in-8 / 16B-unit
    const int sswz = (jj ^ rr) * 8;            // pre-swizzled source unit (ushorts)
    const int l7 = ln & 7;
    const int u0 = (quad ^ l7) * 8;            // K/V hf=0 read unit offset (ushorts)
    const int u1 = u0 ^ 32;                    // hf=1 ( ^4 on the unit index )

    bf16x8 ones;
    {
        union { ushort us[8]; bf16x8 v; } uu;
        #pragma unroll
        for (int p = 0; p < 8; ++p) uu.us[p] = 0x3F80;
        ones = uu.v;
    }
    const f32x4 zero = {0.f, 0.f, 0.f, 0.f};
    const float c1 = 0.125f * 1.44269504f;  // scale*log2e

    // first 256 bids: heavy-first items; second 256: reversed -> heavy+light mix/CU
    const int bid = blockIdx.x;
    const int item = (bid < 256) ? bid : (767 - bid);   // bijection on [0,512)
    const int h = 15 - (item >> 5);
    const int sub = item & 31;
    const int b = sub & 1;
    const int qt = sub >> 1;                 // 0..15, 128 q-rows each
    const int bh = b * 16 + h;
    const int qb0 = qt * 128;
    const int qbw = qb0 + w * 16;            // this wave's 16 q-rows
    const float slope2 = exp2f(-0.5f * (float)(h + 1)) * 1.44269504f;
    const size_t base = (size_t)bh * (TT * HD);

    // ALiBi band (union over the 128 rows); per-wave sub-band for compute skip
    const int D = (int)ceilf(18.0f / slope2);
    int lo = qb0 - D;
    int kt_lo = (lo > 0) ? (lo >> 6) : 0;
    int kt_hi = (qb0 + 128 + D + 63) >> 6;
    if (kt_hi > TT / 64) kt_hi = TT / 64;
    int wl = qbw - D;
    int my_lo = (wl > 0) ? (wl >> 6) : 0;
    if (my_lo < kt_lo) my_lo = kt_lo;
    int my_hi = (qbw + 16 + D + 63) >> 6;
    if (my_hi > kt_hi) my_hi = kt_hi;

    // Q fragments (A-layout) for this wave's 16 rows
    bf16x8 qa[2];
    {
        const uint4* qp = (const uint4*)(Qh + base + (size_t)(qbw + ln) * HD);
        qa[0] = as_bf8(qp[quad]);
        qa[1] = as_bf8(qp[4 + quad]);
    }
    f32x4 o[4], lsum = zero;
    #pragma unroll
    for (int dn = 0; dn < 4; ++dn) o[dn] = zero;
    float qrf[4];
    #pragma unroll
    for (int r = 0; r < 4; ++r)
        qrf[r] = (float)(qbw + quad * 4 + r);

    // stage one K tile (64x64, rows contiguous 128B) + one V tile (64 d-rows x 64 t,
    // rows strided 4KB) into LDS buf; each of the 8 waves stages one 8-row stripe
    // of each (1 gl_lds K + 1 gl_lds V per wave).
    // LDS[r][j] = G[r][j ^ (r&7)]  (source pre-swizzle; dest linear)
    auto STAGE = [&](int bufi, int kt) {
        const int r0 = w * 8;                  // (r0+rr)&7 == rr
#if GLL_LANE
        gl_lds16(Kh + base + (size_t)(kt * 64 + r0 + rr) * HD + sswz, &Ks[bufi][r0][0]);
        gl_lds16(Vtg + base + (size_t)(r0 + rr) * TT + kt * 64 + sswz, &Vs[bufi][r0][0]);
#else
        gl_lds16_fallback(Kh + base + (size_t)(kt * 64 + r0 + rr) * HD + sswz, &Ks[bufi][r0][0], lane);
        gl_lds16_fallback(Vtg + base + (size_t)(r0 + rr) * TT + kt * 64 + sswz, &Vs[bufi][r0][0], lane);
#endif
    };

    STAGE(0, kt_lo);
    int buf = 0;
    for (int kt = kt_lo; kt < kt_hi; ++kt) {
        asm volatile("s_waitcnt vmcnt(0)" ::: "memory");  // my staging for buf done
        __syncthreads();  // everyone's staging done; everyone done reading buf^1
        if (kt + 1 < kt_hi) STAGE(buf ^ 1, kt + 1);

        if (kt >= my_lo && kt < my_hi) {
            // S = Q K^T  (K frags from swizzled LDS)
            f32x4 s[4];
            __builtin_amdgcn_s_setprio(1);
            #pragma unroll
            for (int n = 0; n < 4; ++n) {
                bf16x8 b0 = as_bf8(*(const uint4*)&Ks[buf][n * 16 + ln][u0]);
                bf16x8 b1 = as_bf8(*(const uint4*)&Ks[buf][n * 16 + ln][u1]);
                f32x4 zz = zero;
                zz = __builtin_amdgcn_mfma_f32_16x16x32_bf16(qa[0], b0, zz, 0, 0, 0);
                s[n] = __builtin_amdgcn_mfma_f32_16x16x32_bf16(qa[1], b1, zz, 0, 0, 0);
            }
            __builtin_amdgcn_s_setprio(0);

            // p = exp2(S*c1 - slope2*|q-k|), truncate bf16, swizzled LDS store.
            // phys unit = logical unit ^ (q&7); q = quad*4+r -> q&7 = (quad&1)*4+r
            #pragma unroll
            for (int n = 0; n < 4; ++n) {
                float kg = (float)(kt * 64 + n * 16 + ln);
                const int lun = 2 * n + (ln >> 3);   // logical unit of this lane's k
                #pragma unroll
                for (int r = 0; r < 4; ++r) {
                    float d = qrf[r] - kg;
                    float arg = fmaf(s[n][r], c1, -slope2 * fabsf(d));
                    float p = fexp2(arg);
                    const int bswz = ((lun ^ ((quad & 1) * 4 + r)) * 8) + (ln & 7);
                    Ps[w][quad * 4 + r][bswz] = (ushort)(fasu(p) >> 16);
                }
            }
            // no barrier: Ps[w] is wave-private

            // O += P V ; lsum += P * ones  (V frags from swizzled LDS)
            __builtin_amdgcn_s_setprio(1);
            #pragma unroll
            for (int hf = 0; hf < 2; ++hf) {
                bf16x8 ap = as_bf8(*(const uint4*)&Ps[w][ln][((hf * 4 + quad) ^ (ln & 7)) * 8]);
                const int uu = hf ? u1 : u0;
                #pragma unroll
                for (int dn = 0; dn < 4; ++dn) {
                    bf16x8 bv = as_bf8(*(const uint4*)&Vs[buf][dn * 16 + ln][uu]);
                    o[dn] = __builtin_amdgcn_mfma_f32_16x16x32_bf16(ap, bv, o[dn], 0, 0, 0);
                }
                lsum = __builtin_amdgcn_mfma_f32_16x16x32_bf16(ap, ones, lsum, 0, 0, 0);
            }
            __builtin_amdgcn_s_setprio(0);
        }
        buf ^= 1;
    }

    // -------- epilogue: no merge; each wave owns its 16 rows --------
    #pragma unroll
    for (int r = 0; r < 4; ++r) {
        float inv = __builtin_amdgcn_rcpf(lsum[r]);
        int q = qbw + quad * 4 + r;
        size_t ob = ((size_t)(b * TT + q)) * DD + h * HD;
        #pragma unroll
        for (int dn = 0; dn < 4; ++dn)
            outp[ob + dn * 16 + ln] = f2bf(o[dn][r] * inv);
    }
}

extern "C" void kernel_launch(void* const* d_in, const int* in_sizes, int n_in,
                              void* d_out, int out_size, void* d_ws, size_t ws_size,
                              hipStream_t stream) {
    const float* query = (const float*)d_in[0];
    const float* key   = (const float*)d_in[1];
    const float* value = (const float*)d_in[2];
    const float* Wq = (const float*)d_in[3];
    const float* bq = (const float*)d_in[4];
    const float* Wk = (const float*)d_in[5];
    const float* bk = (const float*)d_in[6];
    const float* Wv = (const float*)d_in[7];
    const float* bv = (const float*)d_in[8];
    const float* Wo = (const float*)d_in[9];
    const float* bo = (const float*)d_in[10];
    float* out = (float*)d_out;

    char* ws = (char*)d_ws;
    const size_t MB = 1024 * 1024;
    ushort* Xq  = (ushort*)(ws + 0);
    ushort* Xk  = (ushort*)(ws + 8 * MB);
    ushort* Xv  = (ushort*)(ws + 16 * MB);
    ushort* Wtq = (ushort*)(ws + 24 * MB);
    ushort* Wtk = (ushort*)(ws + 26 * MB);
    ushort* Wtv = (ushort*)(ws + 28 * MB);
    ushort* Wto = (ushort*)(ws + 30 * MB);
    ushort* Qh  = (ushort*)(ws + 32 * MB);
    ushort* Kh  = (ushort*)(ws + 40 * MB);
    ushort* Vt  = (ushort*)(ws + 48 * MB);  // written transposed by gemm z==2
    ushort* attn = (ushort*)(ws + 0);       // reuse Xq (free after QKV gemm)

    // conversions + weight transpose, one launch
    prep<<<dim3(4096, 4), 256, 0, stream>>>(query, key, value, Wq, Wk, Wv, Wo,
                                            Xq, Xk, Xv, Wtq, Wtk, Wtv, Wto);

    // QKV projections: one z-batched launch; z==2 writes V transposed
    gemm_mfma<128, 0><<<dim3(8, 32, 3), 256, 0, stream>>>(
        Xq, Wtq, bq, Qh,  Xk, Wtk, bk, Kh,  Xv, Wtv, bv, Vt);

    // flash attention: 512 blocks x 512 threads, (b,h,128-q-row) items, 2 blocks/CU
    attn_kernel<<<dim3(512), 512, 0, stream>>>(Qh, Kh, Vt, attn);

    // output projection: 64x128 tiles, 512 blocks (BM=128/256-block variant was
    // ~4us slower: 1 block/CU loses wave overlap)
    gemm_mfma<64, 1><<<dim3(8, 64, 1), 256, 0, stream>>>(
        attn, Wto, bo, out,  attn, Wto, bo, out,  attn, Wto, bo, out);
}